// Round 5
// baseline (90.013 us; speedup 1.0000x reference)
//
#include <hip/hip_runtime.h>
#include <math.h>

// Problem constants (match reference)
#define N_CAM 2
#define PH 96
#define PW 144
#define NPTS 200
#define VD 32
#define VH 128
#define VW 384

constexpr float MIN_DEPTH = 1.0f;
constexpr float MAX_DEPTH = 4000.0f;
constexpr float EPS_T = 1e-10f;
constexpr float VOXEL = 2.5f;

#define SEG 8                       // lanes per ray
#define PIX_PER_BLOCK (256 / SEG)   // 32
#define TOTAL_PIX (N_CAM * PH * PW) // 27648
#define RENDER_BLOCKS (TOTAL_PIX / PIX_PER_BLOCK) // 864 = 8 * 108
#define BEV_BLOCKS ((VH * VW) / 256)              // 192
#define TOTAL_BLOCKS (RENDER_BLOCKS + BEV_BLOCKS) // 1056

// Journal:
// R2: per-block __threadfence() = L2 wb+inv on gfx950, 1056x -> +90us. Never.
// R3: ~3170 same-address device atomicAdds ~6.8ns each serialized -> +21.6us.
//     Per-block plain partial stores + separate reduce kernel instead.
// R5: XCD swizzle — blockIdx%8 maps to XCD; remap so each XCD gets a
//     contiguous 24-row image strip -> per-XCD L2 volume footprint ~8MB
//     instead of ~15-25MB of cross-XCD duplication on the gathers.

__device__ __forceinline__ float huber01(float diff) {
    // (sqrt(1 + diff^2/0.01) - 1) * 0.1 ; always >= 0 so |.| is a no-op
    float t = diff * 10.0f;
    return (sqrtf(fmaf(t, t, 1.0f)) - 1.0f) * 0.1f;
}

__global__ __launch_bounds__(256) void work_kernel(
    const float* __restrict__ dens,      // [VD*VH*VW]
    const float* __restrict__ cols,      // [3*VD*VH*VW] planar
    const float* __restrict__ tsil,      // [N_CAM*PH*PW]
    const float* __restrict__ timg,      // [N_CAM*PH*PW*3]
    const float* __restrict__ focal,     // [N_CAM*2]
    const float* __restrict__ principal, // [N_CAM*2]
    const float* __restrict__ Rm,        // [N_CAM*9]
    const float* __restrict__ Tv,        // [N_CAM*3]
    float* __restrict__ ws)              // [TOTAL_BLOCKS*4] partials
{
    const int tid = threadIdx.x;
    float p0 = 0.f, p1 = 0.f, p2 = 0.f; // block partials (col, sil, bev)

    if (blockIdx.x < RENDER_BLOCKS) {
        // ---------------- render + losses ----------------
        // XCD-aware swizzle: HW assigns XCD = blockIdx % 8 (round-robin).
        // Give XCD k the contiguous pixel-block range [k*108, (k+1)*108)
        // so each XCD's gathers stay inside a ~8MB volume sub-slab.
        const int b  = blockIdx.x;
        const int pb = (b & 7) * (RENDER_BLOCKS / 8) + (b >> 3);

        const int seg = tid & (SEG - 1);
        const int pix = pb * PIX_PER_BLOCK + (tid >> 3);

        const int n   = pix / (PH * PW);
        const int rem = pix - n * (PH * PW);
        const int h   = rem / PW;
        const int w   = rem - h * PW;

        const float dx = ((float)w + 0.5f - principal[n * 2 + 0]) / focal[n * 2 + 0];
        const float dy = ((float)h + 0.5f - principal[n * 2 + 1]) / focal[n * 2 + 1];
        const float* R  = Rm + n * 9;
        const float* Tc = Tv + n * 3;
        const float dwx = R[0] * dx + R[1] * dy + R[2];
        const float dwy = R[3] * dx + R[4] * dy + R[5];
        const float dwz = R[6] * dx + R[7] * dy + R[8];
        const float ox = -(Tc[0] * R[0] + Tc[1] * R[1] + Tc[2] * R[2]);
        const float oy = -(Tc[0] * R[3] + Tc[1] * R[4] + Tc[2] * R[5]);
        const float oz = -(Tc[0] * R[6] + Tc[1] * R[7] + Tc[2] * R[8]);

        const float inv_vox = 1.0f / VOXEL;
        const float bx = (VW - 1) * 0.5f;
        const float by = (VH - 1) * 0.5f;
        const float bz = (VD - 1) * 0.5f;
        const float dstep = (MAX_DEPTH - MIN_DEPTH) / (float)(NPTS - 1);

        // Analytic ray-box clamp in grid space: g_axis(t) in (-1, DIM).
        // Outside samples contribute exactly d=0 -> A,P *= 1.0f exactly in fp32.
        float tn = MIN_DEPTH, tf = MAX_DEPTH;
        {
            const float o3[3] = {ox, oy, oz};
            const float d3[3] = {dwx, dwy, dwz};
            const float b3[3] = {bx, by, bz};
            const float m3[3] = {(float)VW, (float)VH, (float)VD};
            #pragma unroll
            for (int ax = 0; ax < 3; ++ax) {
                const float o = o3[ax], dw = d3[ax], bb = b3[ax], dim = m3[ax];
                if (fabsf(dw) > 1e-12f) {
                    const float ta = ((-1.0f - bb) * VOXEL - o) / dw;
                    const float tb = ((dim  - bb) * VOXEL - o) / dw;
                    tn = fmaxf(tn, fminf(ta, tb));
                    tf = fminf(tf, fmaxf(ta, tb));
                } else {
                    const float g = o * inv_vox + bb;
                    if (!(g > -1.0f && g < dim)) { tn = 1.0f; tf = 0.0f; }
                }
            }
        }
        int k0 = (int)ceilf((tn - MIN_DEPTH) / dstep) - 1;  // -1 margin
        int k1 = (int)floorf((tf - MIN_DEPTH) / dstep) + 2; // exclusive, +1 margin
        k0 = max(k0, 0);
        k1 = min(k1, NPTS);
        if (k1 < k0) k1 = k0;
        const int len = k1 - k0;
        const int L = (len + SEG - 1) / SEG; // contiguous chunk per lane
        const int s0 = k0 + seg * L;
        const int s1 = min(k1, s0 + L);

        float F0 = 0.f, F1 = 0.f, F2 = 0.f;
        float A = 1.0f, P = 1.0f;
        const int S = VD * VH * VW;

        for (int k = s0; k < s1; ++k) {
            const float depth = fmaf((float)k, dstep, MIN_DEPTH);
            const float gx = fmaf(fmaf(depth, dwx, ox), inv_vox, bx);
            const float gy = fmaf(fmaf(depth, dwy, oy), inv_vox, by);
            const float gz = fmaf(fmaf(depth, dwz, oz), inv_vox, bz);

            float d = 0.f, r = 0.f, g = 0.f, b2 = 0.f;
            if (gx > -1.f && gx < (float)VW &&
                gy > -1.f && gy < (float)VH &&
                gz > -1.f && gz < (float)VD) {
                const float x0f = floorf(gx), y0f = floorf(gy), z0f = floorf(gz);
                const float fx = gx - x0f, fy = gy - y0f, fz = gz - z0f;
                const int x0 = (int)x0f, y0 = (int)y0f, z0 = (int)z0f;
                #pragma unroll
                for (int c8 = 0; c8 < 8; ++c8) {
                    const int dxl = c8 & 1, dyl = (c8 >> 1) & 1, dzl = c8 >> 2;
                    const int xi = x0 + dxl, yi = y0 + dyl, zi = z0 + dzl;
                    if (xi < 0 || xi >= VW || yi < 0 || yi >= VH || zi < 0 || zi >= VD)
                        continue;
                    const float wt = (dxl ? fx : 1.f - fx) *
                                     (dyl ? fy : 1.f - fy) *
                                     (dzl ? fz : 1.f - fz);
                    const int flat = (zi * VH + yi) * VW + xi;
                    d  = fmaf(dens[flat],         wt, d);
                    r  = fmaf(cols[flat],         wt, r);
                    g  = fmaf(cols[S + flat],     wt, g);
                    b2 = fmaf(cols[2 * S + flat], wt, b2);
                }
            }
            const float wgt = d * A;
            F0 = fmaf(wgt, r,  F0);
            F1 = fmaf(wgt, g,  F1);
            F2 = fmaf(wgt, b2, F2);
            A *= (1.0f + EPS_T - d);
            P *= (1.0f - d);
        }

        // Combine 8 contiguous segments (lanes) of this ray via shuffle scan.
        float incl = A;
        #pragma unroll
        for (int off = 1; off < SEG; off <<= 1) {
            float t = __shfl_up(incl, off, SEG);
            if (seg >= off) incl *= t;
        }
        float excl = __shfl_up(incl, 1, SEG);
        if (seg == 0) excl = 1.0f;

        float c0 = excl * F0, c1 = excl * F1, c2 = excl * F2;
        #pragma unroll
        for (int m = 1; m < SEG; m <<= 1) {
            c0 += __shfl_xor(c0, m, SEG);
            c1 += __shfl_xor(c1, m, SEG);
            c2 += __shfl_xor(c2, m, SEG);
            P  *= __shfl_xor(P, m, SEG);
        }

        float local_col = 0.f, local_sil = 0.f;
        if (seg == 0) {
            const float opac = 1.0f - P;
            local_sil = huber01(opac - tsil[pix]);
            const float* ti = timg + pix * 3;
            local_col = huber01(c0 - ti[0]) + huber01(c1 - ti[1]) + huber01(c2 - ti[2]);
        }

        #pragma unroll
        for (int m = 1; m < 64; m <<= 1) {
            local_col += __shfl_xor(local_col, m, 64);
            local_sil += __shfl_xor(local_sil, m, 64);
        }
        __shared__ float sc[4], ss[4];
        const int wave = tid >> 6;
        if ((tid & 63) == 0) { sc[wave] = local_col; ss[wave] = local_sil; }
        __syncthreads();
        p0 = sc[0] + sc[1] + sc[2] + sc[3];
        p1 = ss[0] + ss[1] + ss[2] + ss[3];
    } else {
        // ---------------- BEV loss ----------------
        const int t = (blockIdx.x - RENDER_BLOCKS) * 256 + tid; // [0, VH*VW)
        float m = dens[t];
        #pragma unroll
        for (int z = 1; z < VD; ++z)
            m = fmaxf(m, dens[z * (VH * VW) + t]);
        float v = fabsf(m);
        #pragma unroll
        for (int msk = 1; msk < 64; msk <<= 1)
            v += __shfl_xor(v, msk, 64);
        __shared__ float sb[4];
        const int wave = tid >> 6;
        if ((tid & 63) == 0) sb[wave] = v;
        __syncthreads();
        p2 = sb[0] + sb[1] + sb[2] + sb[3];
    }

    // One plain 3-float store per block to a distinct slot. NO atomics.
    if (tid == 0) {
        float* slot = ws + (size_t)blockIdx.x * 4;
        slot[0] = p0;
        slot[1] = p1;
        slot[2] = p2;
    }
}

__global__ __launch_bounds__(256) void finalize_kernel(
    const float* __restrict__ ws, float* __restrict__ out)
{
    const int tid = threadIdx.x;
    float s0 = 0.f, s1 = 0.f, s2 = 0.f;
    for (int i = tid; i < TOTAL_BLOCKS; i += 256) {
        const float* slot = ws + (size_t)i * 4;
        s0 += slot[0];
        s1 += slot[1];
        s2 += slot[2];
    }
    #pragma unroll
    for (int m = 1; m < 64; m <<= 1) {
        s0 += __shfl_xor(s0, m, 64);
        s1 += __shfl_xor(s1, m, 64);
        s2 += __shfl_xor(s2, m, 64);
    }
    __shared__ float a0[4], a1[4], a2[4];
    const int wave = tid >> 6;
    if ((tid & 63) == 0) { a0[wave] = s0; a1[wave] = s1; a2[wave] = s2; }
    __syncthreads();
    if (tid == 0) {
        const float csum = a0[0] + a0[1] + a0[2] + a0[3];
        const float ssum = a1[0] + a1[1] + a1[2] + a1[3];
        const float bsum = a2[0] + a2[1] + a2[2] + a2[3];
        out[0] = csum / (float)(N_CAM * PH * PW * 3); // color_err
        out[1] = ssum / (float)(N_CAM * PH * PW);     // sil_err
        out[2] = bsum / (float)(VH * VW);             // bev_err
    }
}

extern "C" void kernel_launch(void* const* d_in, const int* in_sizes, int n_in,
                              void* d_out, int out_size, void* d_ws, size_t ws_size,
                              hipStream_t stream) {
    const float* dens      = (const float*)d_in[0];
    const float* cols      = (const float*)d_in[1];
    const float* tsil      = (const float*)d_in[2];
    const float* timg      = (const float*)d_in[3];
    const float* focal     = (const float*)d_in[4];
    const float* principal = (const float*)d_in[5];
    const float* Rm        = (const float*)d_in[6];
    const float* Tv        = (const float*)d_in[7];
    float* ws  = (float*)d_ws;
    float* out = (float*)d_out;

    // No memset: every ws slot used is written unconditionally by work_kernel.
    work_kernel<<<TOTAL_BLOCKS, 256, 0, stream>>>(
        dens, cols, tsil, timg, focal, principal, Rm, Tv, ws);
    finalize_kernel<<<1, 256, 0, stream>>>(ws, out);
}

// Round 6
// 88.028 us; speedup vs baseline: 1.0225x; 1.0225x over previous
//
#include <hip/hip_runtime.h>
#include <math.h>

// Problem constants (match reference)
#define N_CAM 2
#define PH 96
#define PW 144
#define NPTS 200
#define VD 32
#define VH 128
#define VW 384

constexpr float MIN_DEPTH = 1.0f;
constexpr float MAX_DEPTH = 4000.0f;
constexpr float EPS_T = 1e-10f;
constexpr float VOXEL = 2.5f;

#define SEG 8                       // lanes per ray
#define PIX_PER_BLOCK (256 / SEG)   // 32
#define TOTAL_PIX (N_CAM * PH * PW) // 27648
#define RENDER_BLOCKS (TOTAL_PIX / PIX_PER_BLOCK) // 864
#define BEV_BLOCKS ((VH * VW) / 256)              // 192
#define TOTAL_BLOCKS (RENDER_BLOCKS + BEV_BLOCKS) // 1056

// Journal:
// R2: per-block __threadfence() = L2 wb+inv on gfx950, 1056x -> +90us. Never.
// R3: ~3170 same-address device atomicAdds ~6.8ns each serialized -> +21.6us.
//     Per-block plain partial stores + separate reduce kernel instead.
// R5: XCD swizzle NEUTRAL/-2.3us (active ~9.4MB footprint is L3-resident;
//     cross-XCD L2 duplication not a real term). Reverted.
// R6: interior fast-path (skip per-corner guards) + rcp-based slab bounds
//     (margins absorb 1-ulp error). Targeting issue/branch overhead.

__device__ __forceinline__ float huber01(float diff) {
    // (sqrt(1 + diff^2/0.01) - 1) * 0.1 ; always >= 0 so |.| is a no-op
    float t = diff * 10.0f;
    return (sqrtf(fmaf(t, t, 1.0f)) - 1.0f) * 0.1f;
}

__global__ __launch_bounds__(256) void work_kernel(
    const float* __restrict__ dens,      // [VD*VH*VW]
    const float* __restrict__ cols,      // [3*VD*VH*VW] planar
    const float* __restrict__ tsil,      // [N_CAM*PH*PW]
    const float* __restrict__ timg,      // [N_CAM*PH*PW*3]
    const float* __restrict__ focal,     // [N_CAM*2]
    const float* __restrict__ principal, // [N_CAM*2]
    const float* __restrict__ Rm,        // [N_CAM*9]
    const float* __restrict__ Tv,        // [N_CAM*3]
    float* __restrict__ ws)              // [TOTAL_BLOCKS*4] partials
{
    const int tid = threadIdx.x;
    float p0 = 0.f, p1 = 0.f, p2 = 0.f; // block partials (col, sil, bev)

    if (blockIdx.x < RENDER_BLOCKS) {
        // ---------------- render + losses ----------------
        const int seg = tid & (SEG - 1);
        const int pix = blockIdx.x * PIX_PER_BLOCK + (tid >> 3);

        const int n   = pix / (PH * PW);
        const int rem = pix - n * (PH * PW);
        const int h   = rem / PW;
        const int w   = rem - h * PW;

        const float dx = ((float)w + 0.5f - principal[n * 2 + 0]) / focal[n * 2 + 0];
        const float dy = ((float)h + 0.5f - principal[n * 2 + 1]) / focal[n * 2 + 1];
        const float* R  = Rm + n * 9;
        const float* Tc = Tv + n * 3;
        const float dwx = R[0] * dx + R[1] * dy + R[2];
        const float dwy = R[3] * dx + R[4] * dy + R[5];
        const float dwz = R[6] * dx + R[7] * dy + R[8];
        const float ox = -(Tc[0] * R[0] + Tc[1] * R[1] + Tc[2] * R[2]);
        const float oy = -(Tc[0] * R[3] + Tc[1] * R[4] + Tc[2] * R[5]);
        const float oz = -(Tc[0] * R[6] + Tc[1] * R[7] + Tc[2] * R[8]);

        const float inv_vox = 1.0f / VOXEL;
        const float bx = (VW - 1) * 0.5f;
        const float by = (VH - 1) * 0.5f;
        const float bz = (VD - 1) * 0.5f;
        const float dstep = (MAX_DEPTH - MIN_DEPTH) / (float)(NPTS - 1);

        // Analytic ray-box clamp in grid space: g_axis(t) in (-1, DIM).
        // Outside samples contribute exactly d=0 -> A,P *= 1.0f exactly in fp32.
        // rcp-based: k0/k1 carry +-1 sample margins, absorbing 1-ulp rcp error.
        float tn = MIN_DEPTH, tf = MAX_DEPTH;
        {
            const float o3[3] = {ox, oy, oz};
            const float d3[3] = {dwx, dwy, dwz};
            const float b3[3] = {bx, by, bz};
            const float m3[3] = {(float)VW, (float)VH, (float)VD};
            #pragma unroll
            for (int ax = 0; ax < 3; ++ax) {
                const float o = o3[ax], dw = d3[ax], bb = b3[ax], dim = m3[ax];
                if (fabsf(dw) > 1e-12f) {
                    const float rdw = __builtin_amdgcn_rcpf(dw);
                    const float ta = ((-1.0f - bb) * VOXEL - o) * rdw;
                    const float tb = ((dim  - bb) * VOXEL - o) * rdw;
                    tn = fmaxf(tn, fminf(ta, tb));
                    tf = fminf(tf, fmaxf(ta, tb));
                } else {
                    const float g = o * inv_vox + bb;
                    if (!(g > -1.0f && g < dim)) { tn = 1.0f; tf = 0.0f; }
                }
            }
        }
        const float rdstep = __builtin_amdgcn_rcpf(dstep);
        int k0 = (int)ceilf((tn - MIN_DEPTH) * rdstep) - 1;  // -1 margin
        int k1 = (int)floorf((tf - MIN_DEPTH) * rdstep) + 2; // exclusive, +1 margin
        k0 = max(k0, 0);
        k1 = min(k1, NPTS);
        if (k1 < k0) k1 = k0;
        const int len = k1 - k0;
        const int L = (len + SEG - 1) / SEG; // contiguous chunk per lane
        const int s0 = k0 + seg * L;
        const int s1 = min(k1, s0 + L);

        float F0 = 0.f, F1 = 0.f, F2 = 0.f;
        float A = 1.0f, P = 1.0f;
        const int S = VD * VH * VW;

        for (int k = s0; k < s1; ++k) {
            const float depth = fmaf((float)k, dstep, MIN_DEPTH);
            const float gx = fmaf(fmaf(depth, dwx, ox), inv_vox, bx);
            const float gy = fmaf(fmaf(depth, dwy, oy), inv_vox, by);
            const float gz = fmaf(fmaf(depth, dwz, oz), inv_vox, bz);

            float d = 0.f, r = 0.f, g = 0.f, b2 = 0.f;
            if (gx > -1.f && gx < (float)VW &&
                gy > -1.f && gy < (float)VH &&
                gz > -1.f && gz < (float)VD) {
                const float x0f = floorf(gx), y0f = floorf(gy), z0f = floorf(gz);
                const float fx = gx - x0f, fy = gy - y0f, fz = gz - z0f;
                const int x0 = (int)x0f, y0 = (int)y0f, z0 = (int)z0f;
                const float wx0 = 1.f - fx, wy0 = 1.f - fy, wz0 = 1.f - fz;

                if (x0 >= 0 && x0 < VW - 1 &&
                    y0 >= 0 && y0 < VH - 1 &&
                    z0 >= 0 && z0 < VD - 1) {
                    // Interior fast path: all 8 corners in-bounds, no guards.
                    const int base = (z0 * VH + y0) * VW + x0;
                    #pragma unroll
                    for (int c8 = 0; c8 < 8; ++c8) {
                        const int dxl = c8 & 1, dyl = (c8 >> 1) & 1, dzl = c8 >> 2;
                        const float wt = (dxl ? fx : wx0) *
                                         (dyl ? fy : wy0) *
                                         (dzl ? fz : wz0);
                        const int flat = base + dzl * (VH * VW) + dyl * VW + dxl;
                        d  = fmaf(dens[flat],         wt, d);
                        r  = fmaf(cols[flat],         wt, r);
                        g  = fmaf(cols[S + flat],     wt, g);
                        b2 = fmaf(cols[2 * S + flat], wt, b2);
                    }
                } else {
                    // Boundary path: per-corner validity (reference semantics).
                    #pragma unroll
                    for (int c8 = 0; c8 < 8; ++c8) {
                        const int dxl = c8 & 1, dyl = (c8 >> 1) & 1, dzl = c8 >> 2;
                        const int xi = x0 + dxl, yi = y0 + dyl, zi = z0 + dzl;
                        if (xi < 0 || xi >= VW || yi < 0 || yi >= VH || zi < 0 || zi >= VD)
                            continue;
                        const float wt = (dxl ? fx : wx0) *
                                         (dyl ? fy : wy0) *
                                         (dzl ? fz : wz0);
                        const int flat = (zi * VH + yi) * VW + xi;
                        d  = fmaf(dens[flat],         wt, d);
                        r  = fmaf(cols[flat],         wt, r);
                        g  = fmaf(cols[S + flat],     wt, g);
                        b2 = fmaf(cols[2 * S + flat], wt, b2);
                    }
                }
            }
            const float wgt = d * A;
            F0 = fmaf(wgt, r,  F0);
            F1 = fmaf(wgt, g,  F1);
            F2 = fmaf(wgt, b2, F2);
            A *= (1.0f + EPS_T - d);
            P *= (1.0f - d);
        }

        // Combine 8 contiguous segments (lanes) of this ray via shuffle scan.
        float incl = A;
        #pragma unroll
        for (int off = 1; off < SEG; off <<= 1) {
            float t = __shfl_up(incl, off, SEG);
            if (seg >= off) incl *= t;
        }
        float excl = __shfl_up(incl, 1, SEG);
        if (seg == 0) excl = 1.0f;

        float c0 = excl * F0, c1 = excl * F1, c2 = excl * F2;
        #pragma unroll
        for (int m = 1; m < SEG; m <<= 1) {
            c0 += __shfl_xor(c0, m, SEG);
            c1 += __shfl_xor(c1, m, SEG);
            c2 += __shfl_xor(c2, m, SEG);
            P  *= __shfl_xor(P, m, SEG);
        }

        float local_col = 0.f, local_sil = 0.f;
        if (seg == 0) {
            const float opac = 1.0f - P;
            local_sil = huber01(opac - tsil[pix]);
            const float* ti = timg + pix * 3;
            local_col = huber01(c0 - ti[0]) + huber01(c1 - ti[1]) + huber01(c2 - ti[2]);
        }

        #pragma unroll
        for (int m = 1; m < 64; m <<= 1) {
            local_col += __shfl_xor(local_col, m, 64);
            local_sil += __shfl_xor(local_sil, m, 64);
        }
        __shared__ float sc[4], ss[4];
        const int wave = tid >> 6;
        if ((tid & 63) == 0) { sc[wave] = local_col; ss[wave] = local_sil; }
        __syncthreads();
        p0 = sc[0] + sc[1] + sc[2] + sc[3];
        p1 = ss[0] + ss[1] + ss[2] + ss[3];
    } else {
        // ---------------- BEV loss ----------------
        const int t = (blockIdx.x - RENDER_BLOCKS) * 256 + tid; // [0, VH*VW)
        float m = dens[t];
        #pragma unroll
        for (int z = 1; z < VD; ++z)
            m = fmaxf(m, dens[z * (VH * VW) + t]);
        float v = fabsf(m);
        #pragma unroll
        for (int msk = 1; msk < 64; msk <<= 1)
            v += __shfl_xor(v, msk, 64);
        __shared__ float sb[4];
        const int wave = tid >> 6;
        if ((tid & 63) == 0) sb[wave] = v;
        __syncthreads();
        p2 = sb[0] + sb[1] + sb[2] + sb[3];
    }

    // One plain 3-float store per block to a distinct slot. NO atomics.
    if (tid == 0) {
        float* slot = ws + (size_t)blockIdx.x * 4;
        slot[0] = p0;
        slot[1] = p1;
        slot[2] = p2;
    }
}

__global__ __launch_bounds__(256) void finalize_kernel(
    const float* __restrict__ ws, float* __restrict__ out)
{
    const int tid = threadIdx.x;
    float s0 = 0.f, s1 = 0.f, s2 = 0.f;
    for (int i = tid; i < TOTAL_BLOCKS; i += 256) {
        const float* slot = ws + (size_t)i * 4;
        s0 += slot[0];
        s1 += slot[1];
        s2 += slot[2];
    }
    #pragma unroll
    for (int m = 1; m < 64; m <<= 1) {
        s0 += __shfl_xor(s0, m, 64);
        s1 += __shfl_xor(s1, m, 64);
        s2 += __shfl_xor(s2, m, 64);
    }
    __shared__ float a0[4], a1[4], a2[4];
    const int wave = tid >> 6;
    if ((tid & 63) == 0) { a0[wave] = s0; a1[wave] = s1; a2[wave] = s2; }
    __syncthreads();
    if (tid == 0) {
        const float csum = a0[0] + a0[1] + a0[2] + a0[3];
        const float ssum = a1[0] + a1[1] + a1[2] + a1[3];
        const float bsum = a2[0] + a2[1] + a2[2] + a2[3];
        out[0] = csum / (float)(N_CAM * PH * PW * 3); // color_err
        out[1] = ssum / (float)(N_CAM * PH * PW);     // sil_err
        out[2] = bsum / (float)(VH * VW);             // bev_err
    }
}

extern "C" void kernel_launch(void* const* d_in, const int* in_sizes, int n_in,
                              void* d_out, int out_size, void* d_ws, size_t ws_size,
                              hipStream_t stream) {
    const float* dens      = (const float*)d_in[0];
    const float* cols      = (const float*)d_in[1];
    const float* tsil      = (const float*)d_in[2];
    const float* timg      = (const float*)d_in[3];
    const float* focal     = (const float*)d_in[4];
    const float* principal = (const float*)d_in[5];
    const float* Rm        = (const float*)d_in[6];
    const float* Tv        = (const float*)d_in[7];
    float* ws  = (float*)d_ws;
    float* out = (float*)d_out;

    // No memset: every ws slot used is written unconditionally by work_kernel.
    work_kernel<<<TOTAL_BLOCKS, 256, 0, stream>>>(
        dens, cols, tsil, timg, focal, principal, Rm, Tv, ws);
    finalize_kernel<<<1, 256, 0, stream>>>(ws, out);
}